// Round 16
// baseline (77.037 us; speedup 1.0000x reference)
//
#include <hip/hip_runtime.h>
#include <hip/hip_fp16.h>

#define BB 16
#define HH 512
#define WW 512
#define NVV 35709
#define NTT 70000
#define HWW (HH * WW)
#define NVTOT (BB * NVV)          // 571344, divisible by 4

// World model (R0-R15, verified):
//   proj_geo, texture, nbl, ori_img : float32
//   is_visible, tri_inds, pixel_valid : int32
//   OUTPUT: float32, concatenated [render BHW3 | real BHW3]
//
// R15 post-mortem: prediction matched (71.0 vs 70+-2); all phases at BW
// floors: prep 74MB/~11us, splat ~3us, compose 335.6MB/~55us. R16: remove
// the record pass entirely -- prep = pure 16.8MB acc zero; splat gathers
// vis (4B x12, ungated) and, for ~12.5% surviving triangles only, proj x,y
// + tex + nbl directly from inputs (f32, no f16 intermediate). Trades
// ~57MB dense prep traffic for ~15-20MB sparse gathers.
//
// acc: u32/px packed {w:5|b:9|g:9|r:9}, colors x64. Integer atomics ->
// order-independent, deterministic. Overflow: per-pixel tri count Poisson
// (lambda<=0.12), P(>=8 hits) ~1e-10; w<=31. Quantization err 1/128.

#define CSCALE 64.0f
#define CINV   0.015625f          // 1/64
#define RMASK  511u

// ---------------------------------------------------------------------------
// zero: grid-stride float4 fill of the acc region.
// ---------------------------------------------------------------------------
__global__ __launch_bounds__(256) void zero_kernel(float4* __restrict__ p, long n4)
{
    long i = (long)blockIdx.x * blockDim.x + threadIdx.x;
    long stride = (long)gridDim.x * blockDim.x;
    float4 z = {0.f, 0.f, 0.f, 0.f};
    for (; i < n4; i += stride) p[i] = z;
}

// ---------------------------------------------------------------------------
// splat: 4 triangles/thread. 3 int4 index loads + 12 x 4B vis gathers
// (ungated, MLP); surviving triangles (~12.5%) gather 6 proj f32 + 9 tex
// + 9 nbl f32 and issue ONE packed u32 atomic.
// ---------------------------------------------------------------------------
__global__ __launch_bounds__(256) void splat_kernel(
    const float* __restrict__ proj,
    const float* __restrict__ tex,
    const float* __restrict__ nbl,
    const int* __restrict__ vis,
    const int4* __restrict__ tri4,    // [NTT*3/4]
    unsigned int* __restrict__ acc,
    int b0)
{
    int g = blockIdx.x * blockDim.x + threadIdx.x;   // 4-triangle group
    if (g >= NTT / 4) return;                        // 17500 groups
    int bl = blockIdx.y;
    int base = (b0 + bl) * NVV;

    int4 wA = tri4[g * 3 + 0];
    int4 wB = tri4[g * 3 + 1];
    int4 wC = tri4[g * 3 + 2];
    int idx[12] = {wA.x, wA.y, wA.z, wA.w, wB.x, wB.y, wB.z, wB.w,
                   wC.x, wC.y, wC.z, wC.w};

    int v[12];
#pragma unroll
    for (int k = 0; k < 12; ++k) v[k] = vis[base + idx[k]];

    long paccb = (long)bl * HWW;
#pragma unroll
    for (int k = 0; k < 4; ++k) {
        // tri_w = min(vis): any invisible vertex kills the splat
        if (v[k * 3 + 0] == 0 || v[k * 3 + 1] == 0 || v[k * 3 + 2] == 0)
            continue;

        long e0 = (long)(base + idx[k * 3 + 0]) * 3;
        long e1 = (long)(base + idx[k * 3 + 1]) * 3;
        long e2 = (long)(base + idx[k * 3 + 2]) * 3;

        float x0 = proj[e0], y0 = proj[e0 + 1];
        float x1 = proj[e1], y1 = proj[e1 + 1];
        float x2 = proj[e2], y2 = proj[e2 + 1];

        float fx = ((x0 + x1) + x2) / 3.0f;   // numpy f32 semantics
        float fy = ((y0 + y1) + y2) / 3.0f;
        int px = (int)rintf(fx);              // round-half-even
        int py = (int)rintf(fy);
        px = min(max(px, 0), WW - 1);
        py = min(max(py, 0), HH - 1);

        // shaded color = tex*nbl, pure f32 (gated gathers)
        float c0r = tex[e0 + 0] * nbl[e0 + 0];
        float c0g = tex[e0 + 1] * nbl[e0 + 1];
        float c0b = tex[e0 + 2] * nbl[e0 + 2];
        float c1r = tex[e1 + 0] * nbl[e1 + 0];
        float c1g = tex[e1 + 1] * nbl[e1 + 1];
        float c1b = tex[e1 + 2] * nbl[e1 + 2];
        float c2r = tex[e2 + 0] * nbl[e2 + 0];
        float c2g = tex[e2 + 1] * nbl[e2 + 1];
        float c2b = tex[e2 + 2] * nbl[e2 + 2];

        float cr = ((c0r + c1r) + c2r) / 3.0f;
        float cg = ((c0g + c1g) + c2g) / 3.0f;
        float cb = ((c0b + c1b) + c2b) / 3.0f;

        unsigned rq = (unsigned)(cr * CSCALE + 0.5f);
        unsigned gq = (unsigned)(cg * CSCALE + 0.5f);
        unsigned bq = (unsigned)(cb * CSCALE + 0.5f);
        unsigned pk = rq | (gq << 9) | (bq << 18) | (1u << 27);

        long lin = paccb + (long)py * WW + px;
        atomicAdd(&acc[lin], pk);
    }
}

// ---------------------------------------------------------------------------
// compose: 4px/thread grid-stride, cached loads, plain cached float4 stores.
// (R13-R15 proven structure — at its mixed-stream floor.)
// ---------------------------------------------------------------------------
__global__ __launch_bounds__(256) void compose_kernel(
    const int4* __restrict__ accv,       // packed u32/px, 4 px per int4
    const float4* __restrict__ oriv,
    const int4* __restrict__ pvv,
    float4* __restrict__ outv,
    int b0, int nb)
{
    long ngrp = (long)nb * (HWW / 4);
    long stride = (long)gridDim.x * blockDim.x;
    const long RO4 = (long)BB * HWW * 3 / 4;   // `real` offset in float4 units

    for (long q = (long)blockIdx.x * blockDim.x + threadIdx.x; q < ngrp;
         q += stride) {
        long qg = (long)b0 * (HWW / 4) + q;                 // global group

        int4 A = accv[q];
        int4 PV = pvv[qg];
        float4 O0 = oriv[qg * 3 + 0];
        float4 O1 = oriv[qg * 3 + 1];
        float4 O2 = oriv[qg * 3 + 2];

        float of[12] = {O0.x, O0.y, O0.z, O0.w, O1.x, O1.y, O1.z, O1.w,
                        O2.x, O2.y, O2.z, O2.w};
        unsigned av[4] = {(unsigned)A.x, (unsigned)A.y,
                          (unsigned)A.z, (unsigned)A.w};
        int pva[4] = {PV.x, PV.y, PV.z, PV.w};

        float rd[12], rl[12];
#pragma unroll
        for (int p = 0; p < 4; ++p) {
            unsigned a = av[p];
            unsigned w = a >> 27;
            bool pv = pva[p] > 0;
            bool cov = (w > 0u) && pv;
            float dninv = cov ? (1.0f / (float)w) : 0.0f;
            float fr = (float)(a & RMASK) * CINV * dninv;
            float fg = (float)((a >> 9) & RMASK) * CINV * dninv;
            float fb = (float)((a >> 18) & RMASK) * CINV * dninv;
            rd[p * 3 + 0] = cov ? fr : of[p * 3 + 0];
            rd[p * 3 + 1] = cov ? fg : of[p * 3 + 1];
            rd[p * 3 + 2] = cov ? fb : of[p * 3 + 2];
            rl[p * 3 + 0] = pv ? of[p * 3 + 0] : 0.f;
            rl[p * 3 + 1] = pv ? of[p * 3 + 1] : 0.f;
            rl[p * 3 + 2] = pv ? of[p * 3 + 2] : 0.f;
        }

        float4 R0 = {rd[0], rd[1], rd[2], rd[3]};
        float4 R1 = {rd[4], rd[5], rd[6], rd[7]};
        float4 R2 = {rd[8], rd[9], rd[10], rd[11]};
        float4 L0 = {rl[0], rl[1], rl[2], rl[3]};
        float4 L1 = {rl[4], rl[5], rl[6], rl[7]};
        float4 L2 = {rl[8], rl[9], rl[10], rl[11]};
        outv[qg * 3 + 0] = R0;
        outv[qg * 3 + 1] = R1;
        outv[qg * 3 + 2] = R2;
        outv[RO4 + qg * 3 + 0] = L0;
        outv[RO4 + qg * 3 + 1] = L1;
        outv[RO4 + qg * 3 + 2] = L2;
    }
}

extern "C" void kernel_launch(void* const* d_in, const int* in_sizes, int n_in,
                              void* d_out, int out_size, void* d_ws, size_t ws_size,
                              hipStream_t stream) {
    const float* proj = (const float*)d_in[0];
    const float* tex  = (const float*)d_in[1];
    const float* nbl  = (const float*)d_in[2];
    const float* ori  = (const float*)d_in[3];
    const int* vis    = (const int*)d_in[4];
    const int* tri    = (const int*)d_in[5];
    const int* pvalid = (const int*)d_in[6];
    float* out        = (float*)d_out;

    const size_t perBatchBytes = (size_t)HWW * 4;      // 1 MiB / batch
    int nbMax = (int)(ws_size / perBatchBytes);
    if (nbMax < 1) nbMax = 1;
    if (nbMax > BB) nbMax = BB;

    for (int b0 = 0; b0 < BB; b0 += nbMax) {
        int nb = (BB - b0 < nbMax) ? (BB - b0) : nbMax;
        unsigned int* acc = (unsigned int*)d_ws;

        long accN4 = (long)nb * HWW / 4;               // float4s (4B/px)
        zero_kernel<<<2048, 256, 0, stream>>>((float4*)d_ws, accN4);

        dim3 gs((NTT / 4 + 255) / 256, nb);
        splat_kernel<<<gs, 256, 0, stream>>>(proj, tex, nbl, vis,
                                             (const int4*)tri, acc, b0);

        compose_kernel<<<2048, 256, 0, stream>>>(
            (const int4*)d_ws, (const float4*)ori, (const int4*)pvalid,
            (float4*)out, b0, nb);
    }
}

// Round 17
// 71.179 us; speedup vs baseline: 1.0823x; 1.0823x over previous
//
#include <hip/hip_runtime.h>
#include <hip/hip_fp16.h>

#define BB 16
#define HH 512
#define WW 512
#define NVV 35709
#define NTT 70000
#define HWW (HH * WW)
#define NVTOT (BB * NVV)          // 571344, divisible by 4

// World model (R0-R16, verified):
//   proj_geo, texture, nbl, ori_img : float32
//   is_visible, tri_inds, pixel_valid : int32
//   OUTPUT: float32, concatenated [render BHW3 | real BHW3]
//
// R16 post-mortem: removing the record pass REGRESSED (77.0 vs 71.0) --
// sparse gated gathers from 3 raw arrays cost more than 57MB dense prep.
// Confirms R8's lesson bidirectionally: dense coalesced precompute + 8B
// record gathers is the splat optimum. This is R15 verbatim (71.0us), the
// measured structural floor:
//   compose 335.6MB mixed ~55us + prep 74.1MB ~11us + splat ~3us + gaps ~2us.
//
// ws layout: Shaded shw[NVTOT] (8 B/vertex: f16 r,g,b, f16 vis)
//            u32 acc[nb*HW] (4 B/pixel, packed {w:5|b:9|g:9|r:9}, colors x64)

typedef float fvec4 __attribute__((ext_vector_type(4)));

struct Shaded { __half2 rg; __half2 bv; };   // 8 B
struct H4 { __half2 a, b, c, d; };           // 16 B = 2 records

#define CSCALE 64.0f
#define CINV   0.015625f          // 1/64
#define RMASK  511u

// ---------------------------------------------------------------------------
// prep: grid-stride. (a) zero acc region (u32/px), (b) build 8B shaded
// records (tex*nbl -> f16, vis flag in .w). No proj traffic.
// ---------------------------------------------------------------------------
__global__ __launch_bounds__(256) void prep_kernel(
    const float4* __restrict__ tex4,
    const float4* __restrict__ nbl4,
    const int4* __restrict__ vis4,
    fvec4* __restrict__ shw4,            // 2 records per fvec4
    float4* __restrict__ accz, long accN4)
{
    long tid = (long)blockIdx.x * blockDim.x + threadIdx.x;
    long stride = (long)gridDim.x * blockDim.x;

    float4 z = {0.f, 0.f, 0.f, 0.f};
    for (long i = tid; i < accN4; i += stride) accz[i] = z;

    for (long q = tid; q < NVTOT / 4; q += stride) {
        float4 T0 = tex4[q * 3 + 0], T1 = tex4[q * 3 + 1], T2 = tex4[q * 3 + 2];
        float4 N0 = nbl4[q * 3 + 0], N1 = nbl4[q * 3 + 1], N2 = nbl4[q * 3 + 2];
        int4 V = vis4[q];

        H4 lo, hi;
        lo.a = __floats2half2_rn(T0.x * N0.x, T0.y * N0.y);            // v0 rg
        lo.b = __floats2half2_rn(T0.z * N0.z, V.x ? 1.f : 0.f);        // v0 bv
        lo.c = __floats2half2_rn(T0.w * N0.w, T1.x * N1.x);            // v1 rg
        lo.d = __floats2half2_rn(T1.y * N1.y, V.y ? 1.f : 0.f);        // v1 bv
        hi.a = __floats2half2_rn(T1.z * N1.z, T1.w * N1.w);            // v2 rg
        hi.b = __floats2half2_rn(T2.x * N2.x, V.z ? 1.f : 0.f);        // v2 bv
        hi.c = __floats2half2_rn(T2.y * N2.y, T2.z * N2.z);            // v3 rg
        hi.d = __floats2half2_rn(T2.w * N2.w, V.w ? 1.f : 0.f);        // v3 bv

        shw4[q * 2 + 0] = __builtin_bit_cast(fvec4, lo);
        shw4[q * 2 + 1] = __builtin_bit_cast(fvec4, hi);
    }
}

// ---------------------------------------------------------------------------
// splat: 4 triangles/thread. 3 int4 index loads + 12 x 8B record gathers
// (ungated, MLP), then per-tri vis gate; SURVIVORS ONLY (~12.5%) load 6 f32
// positions from proj (bit-exact) + one packed u32 atomic.
// ---------------------------------------------------------------------------
__global__ __launch_bounds__(256) void splat_kernel(
    const float* __restrict__ proj,
    const float2* __restrict__ shw,
    const int4* __restrict__ tri4,    // [NTT*3/4]
    unsigned int* __restrict__ acc,
    int b0)
{
    int g = blockIdx.x * blockDim.x + threadIdx.x;   // 4-triangle group
    if (g >= NTT / 4) return;                        // 17500 groups
    int bl = blockIdx.y;
    int base = (b0 + bl) * NVV;

    int4 wA = tri4[g * 3 + 0];
    int4 wB = tri4[g * 3 + 1];
    int4 wC = tri4[g * 3 + 2];
    int idx[12] = {wA.x, wA.y, wA.z, wA.w, wB.x, wB.y, wB.z, wB.w,
                   wC.x, wC.y, wC.z, wC.w};

    float2 rec[12];
#pragma unroll
    for (int k = 0; k < 12; ++k) rec[k] = shw[base + idx[k]];

    long paccb = (long)bl * HWW;
#pragma unroll
    for (int k = 0; k < 4; ++k) {
        Shaded s0 = __builtin_bit_cast(Shaded, rec[k * 3 + 0]);
        Shaded s1 = __builtin_bit_cast(Shaded, rec[k * 3 + 1]);
        Shaded s2 = __builtin_bit_cast(Shaded, rec[k * 3 + 2]);

        // tri_w = min(vis): any invisible vertex kills the splat
        if (__high2float(s0.bv) == 0.f || __high2float(s1.bv) == 0.f ||
            __high2float(s2.bv) == 0.f) continue;

        // positions: gathered only for surviving triangles, raw f32
        long e0 = (long)(base + idx[k * 3 + 0]) * 3;
        long e1 = (long)(base + idx[k * 3 + 1]) * 3;
        long e2 = (long)(base + idx[k * 3 + 2]) * 3;
        float x0 = proj[e0], y0 = proj[e0 + 1];
        float x1 = proj[e1], y1 = proj[e1 + 1];
        float x2 = proj[e2], y2 = proj[e2 + 1];

        float fx = ((x0 + x1) + x2) / 3.0f;   // numpy f32 semantics
        float fy = ((y0 + y1) + y2) / 3.0f;
        int px = (int)rintf(fx);              // round-half-even
        int py = (int)rintf(fy);
        px = min(max(px, 0), WW - 1);
        py = min(max(py, 0), HH - 1);

        float cr = ((__low2float(s0.rg) + __low2float(s1.rg)) + __low2float(s2.rg)) / 3.0f;
        float cg = ((__high2float(s0.rg) + __high2float(s1.rg)) + __high2float(s2.rg)) / 3.0f;
        float cb = ((__low2float(s0.bv) + __low2float(s1.bv)) + __low2float(s2.bv)) / 3.0f;

        unsigned rq = (unsigned)(cr * CSCALE + 0.5f);
        unsigned gq = (unsigned)(cg * CSCALE + 0.5f);
        unsigned bq = (unsigned)(cb * CSCALE + 0.5f);
        unsigned pk = rq | (gq << 9) | (bq << 18) | (1u << 27);

        long lin = paccb + (long)py * WW + px;
        atomicAdd(&acc[lin], pk);
    }
}

// ---------------------------------------------------------------------------
// compose: 4px/thread grid-stride, cached loads, plain cached float4 stores.
// (R13-R15 proven structure — at its mixed-stream floor.)
// ---------------------------------------------------------------------------
__global__ __launch_bounds__(256) void compose_kernel(
    const int4* __restrict__ accv,       // packed u32/px, 4 px per int4
    const float4* __restrict__ oriv,
    const int4* __restrict__ pvv,
    float4* __restrict__ outv,
    int b0, int nb)
{
    long ngrp = (long)nb * (HWW / 4);
    long stride = (long)gridDim.x * blockDim.x;
    const long RO4 = (long)BB * HWW * 3 / 4;   // `real` offset in float4 units

    for (long q = (long)blockIdx.x * blockDim.x + threadIdx.x; q < ngrp;
         q += stride) {
        long qg = (long)b0 * (HWW / 4) + q;                 // global group

        int4 A = accv[q];
        int4 PV = pvv[qg];
        float4 O0 = oriv[qg * 3 + 0];
        float4 O1 = oriv[qg * 3 + 1];
        float4 O2 = oriv[qg * 3 + 2];

        float of[12] = {O0.x, O0.y, O0.z, O0.w, O1.x, O1.y, O1.z, O1.w,
                        O2.x, O2.y, O2.z, O2.w};
        unsigned av[4] = {(unsigned)A.x, (unsigned)A.y,
                          (unsigned)A.z, (unsigned)A.w};
        int pva[4] = {PV.x, PV.y, PV.z, PV.w};

        float rd[12], rl[12];
#pragma unroll
        for (int p = 0; p < 4; ++p) {
            unsigned a = av[p];
            unsigned w = a >> 27;
            bool pv = pva[p] > 0;
            bool cov = (w > 0u) && pv;
            float dninv = cov ? (1.0f / (float)w) : 0.0f;
            float fr = (float)(a & RMASK) * CINV * dninv;
            float fg = (float)((a >> 9) & RMASK) * CINV * dninv;
            float fb = (float)((a >> 18) & RMASK) * CINV * dninv;
            rd[p * 3 + 0] = cov ? fr : of[p * 3 + 0];
            rd[p * 3 + 1] = cov ? fg : of[p * 3 + 1];
            rd[p * 3 + 2] = cov ? fb : of[p * 3 + 2];
            rl[p * 3 + 0] = pv ? of[p * 3 + 0] : 0.f;
            rl[p * 3 + 1] = pv ? of[p * 3 + 1] : 0.f;
            rl[p * 3 + 2] = pv ? of[p * 3 + 2] : 0.f;
        }

        float4 R0 = {rd[0], rd[1], rd[2], rd[3]};
        float4 R1 = {rd[4], rd[5], rd[6], rd[7]};
        float4 R2 = {rd[8], rd[9], rd[10], rd[11]};
        float4 L0 = {rl[0], rl[1], rl[2], rl[3]};
        float4 L1 = {rl[4], rl[5], rl[6], rl[7]};
        float4 L2 = {rl[8], rl[9], rl[10], rl[11]};
        outv[qg * 3 + 0] = R0;
        outv[qg * 3 + 1] = R1;
        outv[qg * 3 + 2] = R2;
        outv[RO4 + qg * 3 + 0] = L0;
        outv[RO4 + qg * 3 + 1] = L1;
        outv[RO4 + qg * 3 + 2] = L2;
    }
}

extern "C" void kernel_launch(void* const* d_in, const int* in_sizes, int n_in,
                              void* d_out, int out_size, void* d_ws, size_t ws_size,
                              hipStream_t stream) {
    const float* proj = (const float*)d_in[0];
    const float* tex  = (const float*)d_in[1];
    const float* nbl  = (const float*)d_in[2];
    const float* ori  = (const float*)d_in[3];
    const int* vis    = (const int*)d_in[4];
    const int* tri    = (const int*)d_in[5];
    const int* pvalid = (const int*)d_in[6];
    float* out        = (float*)d_out;

    const size_t SHBYTES = (size_t)NVTOT * 8;          // 4.57 MB, 16B-aligned
    float2* shw = (float2*)d_ws;
    char* accBase = (char*)d_ws + SHBYTES;

    const size_t perBatchBytes = (size_t)HWW * 4;      // 1 MiB / batch
    size_t remain = (ws_size > SHBYTES) ? ws_size - SHBYTES : 0;
    int nbMax = (int)(remain / perBatchBytes);
    if (nbMax < 1) nbMax = 1;
    if (nbMax > BB) nbMax = BB;

    for (int b0 = 0; b0 < BB; b0 += nbMax) {
        int nb = (BB - b0 < nbMax) ? (BB - b0) : nbMax;
        unsigned int* acc = (unsigned int*)accBase;

        long accN4 = (long)nb * HWW / 4;               // float4s to zero (4B/px)
        prep_kernel<<<2048, 256, 0, stream>>>(
            (const float4*)tex, (const float4*)nbl, (const int4*)vis,
            (fvec4*)shw, (float4*)accBase, accN4);

        dim3 gs((NTT / 4 + 255) / 256, nb);
        splat_kernel<<<gs, 256, 0, stream>>>(proj, shw, (const int4*)tri, acc, b0);

        compose_kernel<<<2048, 256, 0, stream>>>(
            (const int4*)accBase, (const float4*)ori, (const int4*)pvalid,
            (float4*)out, b0, nb);
    }
}